// Round 1
// baseline (1713.216 us; speedup 1.0000x reference)
//
#include <hip/hip_runtime.h>

typedef _Float16 f16;
typedef _Float16 f16x8 __attribute__((ext_vector_type(8)));
typedef float f32x4 __attribute__((ext_vector_type(4)));

#define N_NODES 50000
#define N_EDGES 600000
#define G_GRAPHS 128
#define H 128

// ---------------------------------------------------------------------------
// f0 = relu(node_f @ W_in + b_in)  -> f (f32) and fh (f16)
// ---------------------------------------------------------------------------
__global__ void k_f0(const float* __restrict__ node_f, const float* __restrict__ W_in,
                     const float* __restrict__ b_in, float* __restrict__ f,
                     f16* __restrict__ fh)
{
    __shared__ float sW[32 * 128];   // 16 KB
    __shared__ float sx[8][32];
    const int tid = threadIdx.x;     // 128 threads
    const int base = blockIdx.x * 8;
    for (int i = tid; i < 32 * 128; i += 128) sW[i] = W_in[i];
    for (int i = tid; i < 8 * 32; i += 128) {
        int u = i >> 5, k = i & 31;
        int n = base + u;
        sx[u][k] = (n < N_NODES) ? node_f[(size_t)n * 32 + k] : 0.0f;
    }
    __syncthreads();
    const float bj = b_in[tid];
    #pragma unroll
    for (int u = 0; u < 8; ++u) {
        int n = base + u;
        if (n >= N_NODES) break;
        float acc = bj;
        #pragma unroll
        for (int k = 0; k < 32; ++k) acc = fmaf(sx[u][k], sW[k * 128 + tid], acc);
        float r = fmaxf(acc, 0.0f);
        f[(size_t)n * H + tid] = r;
        fh[(size_t)n * H + tid] = (f16)r;
    }
}

// ---------------------------------------------------------------------------
// sq[e] = ||x[src]-x[dst]||^2
// ---------------------------------------------------------------------------
__global__ void k_sq(const float* __restrict__ node_x, const int* __restrict__ src,
                     const int* __restrict__ dst, float* __restrict__ sq)
{
    int e = blockIdx.x * 256 + threadIdx.x;
    if (e >= N_EDGES) return;
    int s = src[e], d = dst[e];
    float dx = node_x[s * 3 + 0] - node_x[d * 3 + 0];
    float dy = node_x[s * 3 + 1] - node_x[d * 3 + 1];
    float dz = node_x[s * 3 + 2] - node_x[d * 3 + 2];
    sq[e] = dx * dx + dy * dy + dz * dz;
}

// ---------------------------------------------------------------------------
// Fused edge kernel: w = relu(edge_w@We+be); mi=[f_src|f_dst|w|sq];
// m = relu(relu(mi@W1+b1)@W2+b2); atomic scatter to m_sum[dst]
// ---------------------------------------------------------------------------
__global__ __launch_bounds__(256, 2) void k_edge(
    const f16* __restrict__ fh, const float* __restrict__ edge_w,
    const int* __restrict__ src, const int* __restrict__ dst,
    const float* __restrict__ sq,
    const float* __restrict__ W_e, const float* __restrict__ b_e,
    const float* __restrict__ W1, const float* __restrict__ b1,
    const float* __restrict__ W2, const float* __restrict__ b2,
    float* __restrict__ m_sum)
{
    const int tid = threadIdx.x;
    const int wave = tid >> 6;
    const int lane = tid & 63;
    const int l16 = lane & 15;
    const int lq = lane >> 4;
    const int colbase = wave * 32;   // this wave owns output cols [colbase, colbase+32)

    // ---- weight B-fragments in registers ----
    f16x8 w1f[12][2];
    f16x8 w2f[4][2];
    f16x8 wef[2];
    float w1last[2], b1v[2], b2v[2], bev[2];
    #pragma unroll
    for (int nt = 0; nt < 2; ++nt) {
        const int col = colbase + nt * 16 + l16;
        #pragma unroll
        for (int k = 0; k < 12; ++k) {
            f16x8 v;
            #pragma unroll
            for (int j = 0; j < 8; ++j)
                v[j] = (f16)W1[(size_t)(k * 32 + lq * 8 + j) * H + col];
            w1f[k][nt] = v;
        }
        #pragma unroll
        for (int k = 0; k < 4; ++k) {
            f16x8 v;
            #pragma unroll
            for (int j = 0; j < 8; ++j)
                v[j] = (f16)W2[(size_t)(k * 32 + lq * 8 + j) * H + col];
            w2f[k][nt] = v;
        }
        {
            f16x8 v;
            #pragma unroll
            for (int j = 0; j < 8; ++j) {
                int k = lq * 8 + j;
                v[j] = (k < 16) ? (f16)W_e[(size_t)k * H + col] : (f16)0.0f;
            }
            wef[nt] = v;
        }
        w1last[nt] = W1[(size_t)384 * H + col];
        b1v[nt] = b1[col];
        b2v[nt] = b2[col];
        bev[nt] = b_e[col];
    }

    __shared__ alignas(16) f16 Atile[32][392];   // 392 = 384 + 8 pad (bank stagger)
    __shared__ int s_src[32];
    __shared__ int s_dst[32];
    __shared__ float s_sq[32];

    const int nTiles = N_EDGES / 32;   // 18750 exactly
    for (int tile = blockIdx.x; tile < nTiles; tile += gridDim.x) {
        __syncthreads();               // protect LDS from previous iteration
        const int e0 = tile * 32;
        if (tid < 32) {
            s_src[tid] = src[e0 + tid];
            s_dst[tid] = dst[e0 + tid];
            s_sq[tid]  = sq[e0 + tid];
        }
        __syncthreads();

        // stage f[src] -> cols 0..127, f[dst] -> cols 128..255 (f16, 2x16B per thread)
        {
            const int row = tid >> 3;
            const int ch  = tid & 7;
            const int4* ps = (const int4*)fh + (size_t)s_src[row] * 16 + ch * 2;
            const int4* pd = (const int4*)fh + (size_t)s_dst[row] * 16 + ch * 2;
            int4* q1 = (int4*)(&Atile[row][0]) + ch * 2;
            int4* q2 = (int4*)(&Atile[row][128]) + ch * 2;
            q1[0] = ps[0]; q1[1] = ps[1];
            q2[0] = pd[0]; q2[1] = pd[1];
        }

        // edge_w A-fragments (K padded 16->32 with zeros)
        f16x8 aef[2];
        #pragma unroll
        for (int m = 0; m < 2; ++m) {
            f16x8 v;
            const int erow = e0 + m * 16 + l16;
            #pragma unroll
            for (int j = 0; j < 8; ++j) {
                int k = lq * 8 + j;
                v[j] = (k < 16) ? (f16)edge_w[(size_t)erow * 16 + k] : (f16)0.0f;
            }
            aef[m] = v;
        }

        // w-tile = relu(edge_w@We + be) -> Atile cols 256..383
        #pragma unroll
        for (int m = 0; m < 2; ++m) {
            #pragma unroll
            for (int nt = 0; nt < 2; ++nt) {
                f32x4 c = {bev[nt], bev[nt], bev[nt], bev[nt]};
                c = __builtin_amdgcn_mfma_f32_16x16x32_f16(aef[m], wef[nt], c, 0, 0, 0);
                #pragma unroll
                for (int r = 0; r < 4; ++r) {
                    int row = m * 16 + lq * 4 + r;
                    int col = colbase + nt * 16 + l16;
                    Atile[row][256 + col] = (f16)fmaxf(c[r], 0.0f);
                }
            }
        }
        __syncthreads();

        // matmul1: h1 = relu(A @ W1[0:384] + sq*W1[384] + b1)
        f32x4 acc[2][2];
        #pragma unroll
        for (int m = 0; m < 2; ++m)
            #pragma unroll
            for (int nt = 0; nt < 2; ++nt)
                #pragma unroll
                for (int r = 0; r < 4; ++r)
                    acc[m][nt][r] = fmaf(s_sq[m * 16 + lq * 4 + r], w1last[nt], b1v[nt]);
        #pragma unroll
        for (int k = 0; k < 12; ++k) {
            #pragma unroll
            for (int m = 0; m < 2; ++m) {
                f16x8 a = *(const f16x8*)(&Atile[m * 16 + l16][k * 32 + lq * 8]);
                #pragma unroll
                for (int nt = 0; nt < 2; ++nt)
                    acc[m][nt] = __builtin_amdgcn_mfma_f32_16x16x32_f16(a, w1f[k][nt], acc[m][nt], 0, 0, 0);
            }
        }
        __syncthreads();   // all A reads done before h1 overwrite

        // h1 (f16) -> Atile cols 0..127
        #pragma unroll
        for (int m = 0; m < 2; ++m)
            #pragma unroll
            for (int nt = 0; nt < 2; ++nt)
                #pragma unroll
                for (int r = 0; r < 4; ++r) {
                    int row = m * 16 + lq * 4 + r;
                    int col = colbase + nt * 16 + l16;
                    Atile[row][col] = (f16)fmaxf(acc[m][nt][r], 0.0f);
                }
        __syncthreads();

        // matmul2: m = relu(h1 @ W2 + b2), then atomic scatter to m_sum[dst]
        f32x4 acc2[2][2];
        #pragma unroll
        for (int m = 0; m < 2; ++m)
            #pragma unroll
            for (int nt = 0; nt < 2; ++nt) {
                f32x4 c = {b2v[nt], b2v[nt], b2v[nt], b2v[nt]};
                acc2[m][nt] = c;
            }
        #pragma unroll
        for (int k = 0; k < 4; ++k) {
            #pragma unroll
            for (int m = 0; m < 2; ++m) {
                f16x8 a = *(const f16x8*)(&Atile[m * 16 + l16][k * 32 + lq * 8]);
                #pragma unroll
                for (int nt = 0; nt < 2; ++nt)
                    acc2[m][nt] = __builtin_amdgcn_mfma_f32_16x16x32_f16(a, w2f[k][nt], acc2[m][nt], 0, 0, 0);
            }
        }
        #pragma unroll
        for (int m = 0; m < 2; ++m)
            #pragma unroll
            for (int nt = 0; nt < 2; ++nt)
                #pragma unroll
                for (int r = 0; r < 4; ++r) {
                    int row = m * 16 + lq * 4 + r;
                    int col = colbase + nt * 16 + l16;
                    float v = fmaxf(acc2[m][nt][r], 0.0f);
                    unsafeAtomicAdd(&m_sum[(size_t)s_dst[row] * H + col], v);
                }
    }
}

// ---------------------------------------------------------------------------
// Node update: f = relu(relu((m_sum+f)@U1+b1)@U2+b2)   (in-place on f, + fh)
// ---------------------------------------------------------------------------
__global__ __launch_bounds__(256, 4) void k_update(
    const float* __restrict__ m_sum, const float* __restrict__ f_in,
    const float* __restrict__ W1, const float* __restrict__ b1,
    const float* __restrict__ W2, const float* __restrict__ b2,
    float* __restrict__ f_out, f16* __restrict__ fh_out)
{
    const int tid = threadIdx.x;
    const int wave = tid >> 6;
    const int lane = tid & 63;
    const int l16 = lane & 15;
    const int lq = lane >> 4;
    const int colbase = wave * 32;

    f16x8 w1fr[4][2], w2fr[4][2];
    float b1v[2], b2v[2];
    #pragma unroll
    for (int nt = 0; nt < 2; ++nt) {
        const int col = colbase + nt * 16 + l16;
        #pragma unroll
        for (int k = 0; k < 4; ++k) {
            f16x8 v1, v2;
            #pragma unroll
            for (int j = 0; j < 8; ++j) {
                v1[j] = (f16)W1[(size_t)(k * 32 + lq * 8 + j) * H + col];
                v2[j] = (f16)W2[(size_t)(k * 32 + lq * 8 + j) * H + col];
            }
            w1fr[k][nt] = v1;
            w2fr[k][nt] = v2;
        }
        b1v[nt] = b1[col];
        b2v[nt] = b2[col];
    }

    __shared__ alignas(16) f16 U[32][136];
    const int nTiles = (N_NODES + 31) / 32;
    for (int tile = blockIdx.x; tile < nTiles; tile += gridDim.x) {
        __syncthreads();
        const int n0 = tile * 32;
        {
            const int row = tid >> 3;
            const int ch  = tid & 7;
            const int n = n0 + row;
            if (n < N_NODES) {
                const float4* pm = (const float4*)(m_sum + (size_t)n * H) + ch * 4;
                const float4* pf = (const float4*)(f_in + (size_t)n * H) + ch * 4;
                f16 tmp[16];
                #pragma unroll
                for (int q = 0; q < 4; ++q) {
                    float4 a = pm[q], b = pf[q];
                    tmp[q * 4 + 0] = (f16)(a.x + b.x);
                    tmp[q * 4 + 1] = (f16)(a.y + b.y);
                    tmp[q * 4 + 2] = (f16)(a.z + b.z);
                    tmp[q * 4 + 3] = (f16)(a.w + b.w);
                }
                int4* q0 = (int4*)(&U[row][ch * 16]);
                q0[0] = ((const int4*)tmp)[0];
                q0[1] = ((const int4*)tmp)[1];
            }
        }
        __syncthreads();

        f32x4 acc[2][2];
        #pragma unroll
        for (int m = 0; m < 2; ++m)
            #pragma unroll
            for (int nt = 0; nt < 2; ++nt) {
                f32x4 c = {b1v[nt], b1v[nt], b1v[nt], b1v[nt]};
                acc[m][nt] = c;
            }
        #pragma unroll
        for (int k = 0; k < 4; ++k) {
            #pragma unroll
            for (int m = 0; m < 2; ++m) {
                f16x8 a = *(const f16x8*)(&U[m * 16 + l16][k * 32 + lq * 8]);
                #pragma unroll
                for (int nt = 0; nt < 2; ++nt)
                    acc[m][nt] = __builtin_amdgcn_mfma_f32_16x16x32_f16(a, w1fr[k][nt], acc[m][nt], 0, 0, 0);
            }
        }
        __syncthreads();
        #pragma unroll
        for (int m = 0; m < 2; ++m)
            #pragma unroll
            for (int nt = 0; nt < 2; ++nt)
                #pragma unroll
                for (int r = 0; r < 4; ++r) {
                    int row = m * 16 + lq * 4 + r;
                    int col = colbase + nt * 16 + l16;
                    U[row][col] = (f16)fmaxf(acc[m][nt][r], 0.0f);
                }
        __syncthreads();

        f32x4 acc2[2][2];
        #pragma unroll
        for (int m = 0; m < 2; ++m)
            #pragma unroll
            for (int nt = 0; nt < 2; ++nt) {
                f32x4 c = {b2v[nt], b2v[nt], b2v[nt], b2v[nt]};
                acc2[m][nt] = c;
            }
        #pragma unroll
        for (int k = 0; k < 4; ++k) {
            #pragma unroll
            for (int m = 0; m < 2; ++m) {
                f16x8 a = *(const f16x8*)(&U[m * 16 + l16][k * 32 + lq * 8]);
                #pragma unroll
                for (int nt = 0; nt < 2; ++nt)
                    acc2[m][nt] = __builtin_amdgcn_mfma_f32_16x16x32_f16(a, w2fr[k][nt], acc2[m][nt], 0, 0, 0);
            }
        }
        #pragma unroll
        for (int m = 0; m < 2; ++m)
            #pragma unroll
            for (int nt = 0; nt < 2; ++nt)
                #pragma unroll
                for (int r = 0; r < 4; ++r) {
                    int row = m * 16 + lq * 4 + r;
                    int n = n0 + row;
                    if (n < N_NODES) {
                        int col = colbase + nt * 16 + l16;
                        float v = fmaxf(acc2[m][nt][r], 0.0f);
                        f_out[(size_t)n * H + col] = v;
                        fh_out[(size_t)n * H + col] = (f16)v;
                    }
                }
    }
}

// ---------------------------------------------------------------------------
// Per-graph mean/max readout (graph_ids sorted; f >= 0 so int-punned atomicMax)
// ---------------------------------------------------------------------------
__global__ void k_readout(const float* __restrict__ f, const int* __restrict__ gid,
                          float* __restrict__ gsum, float* __restrict__ gmax,
                          int* __restrict__ gcnt)
{
    __shared__ int s_gid[64];
    const int tid = threadIdx.x;            // 128 threads
    const int base = blockIdx.x * 64;
    if (tid < 64) s_gid[tid] = (base + tid < N_NODES) ? gid[base + tid] : -1;
    __syncthreads();
    if (tid < 64 && base + tid < N_NODES) atomicAdd(&gcnt[s_gid[tid]], 1);

    float lsum = 0.0f, lmax = 0.0f;
    int cur = s_gid[0];
    if (cur >= 0) {
        for (int i = 0; i < 64; ++i) {
            int g = s_gid[i];
            if (g < 0) break;
            if (g != cur) {
                unsafeAtomicAdd(&gsum[(size_t)cur * H + tid], lsum);
                atomicMax((int*)&gmax[(size_t)cur * H + tid], __float_as_int(lmax));
                lsum = 0.0f; lmax = 0.0f; cur = g;
            }
            float v = f[(size_t)(base + i) * H + tid];
            lsum += v;
            lmax = fmaxf(lmax, v);
        }
        unsafeAtomicAdd(&gsum[(size_t)cur * H + tid], lsum);
        atomicMax((int*)&gmax[(size_t)cur * H + tid], __float_as_int(lmax));
    }
}

// ---------------------------------------------------------------------------
// out = [mean | max] @ W_out + b_out
// ---------------------------------------------------------------------------
__global__ void k_out(const float* __restrict__ gsum, const float* __restrict__ gmax,
                      const int* __restrict__ gcnt, const float* __restrict__ W_out,
                      const float* __restrict__ b_out, float* __restrict__ out)
{
    __shared__ float sm[128], sx[128];
    const int g = blockIdx.x, t = threadIdx.x;
    const float inv = 1.0f / fmaxf((float)gcnt[g], 1.0f);
    sm[t] = gsum[(size_t)g * H + t] * inv;
    sx[t] = gmax[(size_t)g * H + t];
    __syncthreads();
    float acc = b_out[t];
    for (int k = 0; k < H; ++k) {
        acc = fmaf(sm[k], W_out[(size_t)k * 128 + t], acc);
        acc = fmaf(sx[k], W_out[(size_t)(128 + k) * 128 + t], acc);
    }
    out[(size_t)g * 128 + t] = acc;
}

// ---------------------------------------------------------------------------
extern "C" void kernel_launch(void* const* d_in, const int* in_sizes, int n_in,
                              void* d_out, int out_size, void* d_ws, size_t ws_size,
                              hipStream_t stream)
{
    const float* node_f = (const float*)d_in[0];
    const float* node_x = (const float*)d_in[1];
    const float* edge_w = (const float*)d_in[2];
    const int*   src    = (const int*)d_in[3];
    const int*   dst    = (const int*)d_in[4];
    const int*   gid    = (const int*)d_in[5];
    const float* W_in   = (const float*)d_in[6];
    const float* b_in   = (const float*)d_in[7];
    const float* W_e    = (const float*)d_in[8];
    const float* b_e    = (const float*)d_in[9];
    const float* msg_W1 = (const float*)d_in[10];
    const float* msg_b1 = (const float*)d_in[11];
    const float* msg_W2 = (const float*)d_in[12];
    const float* msg_b2 = (const float*)d_in[13];
    const float* upd_W1 = (const float*)d_in[14];
    const float* upd_b1 = (const float*)d_in[15];
    const float* upd_W2 = (const float*)d_in[16];
    const float* upd_b2 = (const float*)d_in[17];
    const float* W_out  = (const float*)d_in[18];
    const float* b_out  = (const float*)d_in[19];
    float* out = (float*)d_out;

    char* ws = (char*)d_ws;
    size_t off = 0;
    float* f    = (float*)(ws + off); off += (size_t)N_NODES * H * 4;   // 25.6 MB
    f16*   fh   = (f16*)(ws + off);   off += (size_t)N_NODES * H * 2;   // 12.8 MB
    float* msum = (float*)(ws + off); off += (size_t)N_NODES * H * 4;   // 25.6 MB
    float* sq   = (float*)(ws + off); off += (size_t)N_EDGES * 4;       // 2.4 MB
    float* gsum = (float*)(ws + off); off += (size_t)G_GRAPHS * H * 4;
    float* gmax = (float*)(ws + off); off += (size_t)G_GRAPHS * H * 4;
    int*   gcnt = (int*)(ws + off);   off += (size_t)G_GRAPHS * 4;

    k_f0<<<(N_NODES + 7) / 8, 128, 0, stream>>>(node_f, W_in, b_in, f, fh);
    k_sq<<<(N_EDGES + 255) / 256, 256, 0, stream>>>(node_x, src, dst, sq);

    for (int l = 0; l < 4; ++l) {
        hipMemsetAsync(msum, 0, (size_t)N_NODES * H * 4, stream);
        k_edge<<<512, 256, 0, stream>>>(fh, edge_w, src, dst, sq, W_e, b_e,
                                        msg_W1 + (size_t)l * 385 * H, msg_b1 + (size_t)l * H,
                                        msg_W2 + (size_t)l * H * H,  msg_b2 + (size_t)l * H,
                                        msum);
        k_update<<<512, 256, 0, stream>>>(msum, f,
                                          upd_W1 + (size_t)l * H * H, upd_b1 + (size_t)l * H,
                                          upd_W2 + (size_t)l * H * H, upd_b2 + (size_t)l * H,
                                          f, fh);
    }

    hipMemsetAsync(gsum, 0, (size_t)G_GRAPHS * H * 4, stream);
    hipMemsetAsync(gmax, 0, (size_t)G_GRAPHS * H * 4, stream);
    hipMemsetAsync(gcnt, 0, (size_t)G_GRAPHS * 4, stream);
    k_readout<<<(N_NODES + 63) / 64, 128, 0, stream>>>(f, gid, gsum, gmax, gcnt);
    k_out<<<G_GRAPHS, 128, 0, stream>>>(gsum, gmax, gcnt, W_out, b_out, out);
}